// Round 3
// baseline (1016.494 us; speedup 1.0000x reference)
//
#include <hip/hip_runtime.h>
#include <hip/hip_fp16.h>
#include <math.h>

// B=32, N=1024 Sinkhorn (20 iters). scores@W+b cancels under the first row-lse
// -> inputs 0..2 dead. Linear domain: K = exp(g-8) fp16 held in REGISTERS of a
// persistent 256-block grid (8 blocks/batch, thread = 128-col strided strip x
// 16 rows). Row step block-local; col step exchanges 4KB/block via global ws +
// device-scope batch barrier (double-buffered, 1 barrier/iter).
#define BB 32
#define NN 1024
#define SHIFT 8.0f

typedef _Float16 h2 __attribute__((ext_vector_type(2)));

__global__ void init_ctr(unsigned* ctr) {
    if (threadIdx.x < BB) ctr[threadIdx.x] = 0u;
}

__global__ __launch_bounds__(1024) void sinkhorn_persist(
        const float* __restrict__ g, float* __restrict__ out,
        float* __restrict__ wscol, unsigned* __restrict__ ctr) {
    const int tid   = threadIdx.x;
    const int batch = blockIdx.x & 31;   // slabs of a batch land on same XCD (%8 heuristic)
    const int slab  = blockIdx.x >> 5;
    const int cg = tid & 127;            // column group: cols cg + 128*jo, jo=0..7
    const int rg = tid >> 7;             // row group: rows slab*128 + rg*16 + r

    // LDS: pool shared between row-partials [64][129] (33KB) and col buffer [8][1024] (32KB)
    __shared__ float lds_pool[64 * 129];
    __shared__ float lds_u[128];
    __shared__ float lds_v[1024];
    float (*lds_part)[129] = (float(*)[129])lds_pool;
    float (*lds_col)[1024] = (float(*)[1024])lds_pool;

    // ---- build K = fp16(exp(g-8)) in registers: kk[r][jp] = cols (cg+256jp, cg+256jp+128)
    h2 kk[16][4];
    const size_t rowbase = (((size_t)(batch << 10) + slab * 128 + rg * 16) << 10);
    const float* gb = g + rowbase + cg;
    #pragma unroll
    for (int r = 0; r < 16; ++r) {
        #pragma unroll
        for (int jp = 0; jp < 4; ++jp) {
            float a = gb[(r << 10) + 256 * jp];
            float b = gb[(r << 10) + 256 * jp + 128];
            h2 h;
            h.x = (_Float16)__expf(a - SHIFT);
            h.y = (_Float16)__expf(b - SHIFT);
            kk[r][jp] = h;
        }
    }
    h2 vv[4];
    #pragma unroll
    for (int jp = 0; jp < 4; ++jp) { vv[jp].x = (_Float16)1.f; vv[jp].y = (_Float16)1.f; }

    float uf[16];
    const int ro2 = tid >> 4;            // 0..63  (reduce-phase row)
    const int s16 = tid & 15;            // 0..15  (reduce-phase chunk)

    for (int it = 0; it < 20; ++it) {
        // ---- row step: u[r] = 1/sum_j K[r][j] v[j] (block-local) ----
        float acc[16];
        #pragma unroll
        for (int r = 0; r < 16; ++r) {
            float a = 0.f;
            #pragma unroll
            for (int jp = 0; jp < 4; ++jp) {
                a = fmaf((float)kk[r][jp].x, (float)vv[jp].x, a);
                a = fmaf((float)kk[r][jp].y, (float)vv[jp].y, a);
            }
            acc[r] = a;
        }
        #pragma unroll
        for (int h = 0; h < 2; ++h) {    // two-phase: rows [64h, 64h+64)
            if ((rg >> 2) == h) {
                #pragma unroll
                for (int r = 0; r < 16; ++r) lds_part[(rg & 3) * 16 + r][cg] = acc[r];
            }
            __syncthreads();
            const float* pp = &lds_part[ro2][s16 * 8];
            float a = 0.f;
            #pragma unroll
            for (int k = 0; k < 8; ++k) a += pp[k];
            a += __shfl_down(a, 8);
            a += __shfl_down(a, 4);
            a += __shfl_down(a, 2);
            a += __shfl_down(a, 1);
            if (s16 == 0) lds_u[64 * h + ro2] = __builtin_amdgcn_rcpf(a);
            __syncthreads();
        }
        // ---- col step partials: cp[jo] = sum_{r in slab-band} K[r][jo-col] * u[r] ----
        #pragma unroll
        for (int k = 0; k < 16; ++k) uf[k] = lds_u[rg * 16 + k];   // wave-uniform broadcast
        float cp[8] = {0.f,0.f,0.f,0.f,0.f,0.f,0.f,0.f};
        #pragma unroll
        for (int r = 0; r < 16; ++r) {
            #pragma unroll
            for (int jp = 0; jp < 4; ++jp) {
                cp[2*jp]   = fmaf((float)kk[r][jp].x, uf[r], cp[2*jp]);
                cp[2*jp+1] = fmaf((float)kk[r][jp].y, uf[r], cp[2*jp+1]);
            }
        }
        #pragma unroll
        for (int jo = 0; jo < 8; ++jo) lds_col[rg][cg + 128 * jo] = cp[jo];
        __syncthreads();
        float csum = lds_col[0][tid];
        #pragma unroll
        for (int s2 = 1; s2 < 8; ++s2) csum += lds_col[s2][tid];
        // ---- cross-block exchange (double-buffered) + device-scope batch barrier ----
        const int buf = it & 1;
        float* wc = wscol + (size_t)((((buf * BB + batch) << 3) + slab) << 10);
        __hip_atomic_store(&wc[tid], csum, __ATOMIC_RELAXED, __HIP_MEMORY_SCOPE_AGENT);
        __syncthreads();                          // drains vmcnt: all stores complete
        if (tid == 0) {
            __hip_atomic_fetch_add(&ctr[batch], 1u, __ATOMIC_RELEASE, __HIP_MEMORY_SCOPE_AGENT);
            const unsigned target = 8u * (unsigned)(it + 1);
            while (__hip_atomic_load(&ctr[batch], __ATOMIC_ACQUIRE, __HIP_MEMORY_SCOPE_AGENT) < target)
                __builtin_amdgcn_s_sleep(4);
        }
        __syncthreads();
        // ---- v update: v[j] = 1/sum over 8 slabs ----
        const float* wr = wscol + (size_t)(((buf * BB + batch) << 3) << 10) + tid;
        float vsum = 0.f;
        #pragma unroll
        for (int s2 = 0; s2 < 8; ++s2)
            vsum += __hip_atomic_load(&wr[(size_t)s2 << 10], __ATOMIC_RELAXED, __HIP_MEMORY_SCOPE_AGENT);
        lds_v[tid] = __builtin_amdgcn_rcpf(vsum);
        __syncthreads();
        #pragma unroll
        for (int jp = 0; jp < 4; ++jp) {
            h2 h;
            h.x = (_Float16)lds_v[cg + 256 * jp];
            h.y = (_Float16)lds_v[cg + 256 * jp + 128];
            vv[jp] = h;
        }
    }
    // ---- finalize: out = K * u_i * v_j (u from iter-19 row step, v final) ----
    float vf[8];
    #pragma unroll
    for (int jo = 0; jo < 8; ++jo) vf[jo] = lds_v[cg + 128 * jo];
    float* ob = out + rowbase + cg;
    #pragma unroll
    for (int r = 0; r < 16; ++r) {
        const float ur = uf[r];
        #pragma unroll
        for (int jp = 0; jp < 4; ++jp) {
            ob[(r << 10) + 256 * jp]       = (float)kk[r][jp].x * ur * vf[2*jp];
            ob[(r << 10) + 256 * jp + 128] = (float)kk[r][jp].y * ur * vf[2*jp+1];
        }
    }
}

// ---------- fallback (log-domain, tiny ws) ----------
template<bool USE_V>
__global__ __launch_bounds__(256) void row_step(const float* __restrict__ g,
                                                const float* __restrict__ v,
                                                float* __restrict__ t) {
    const int wave = threadIdx.x >> 6, lane = threadIdx.x & 63;
    const int row = blockIdx.x * 4 + wave;
    const int b = row >> 10;
    const float4* grow = (const float4*)(g + ((size_t)row << 10));
    const float4* vrow = (const float4*)(v + ((size_t)b << 10));
    float x[16];
    #pragma unroll
    for (int k = 0; k < 4; k++) {
        float4 gg = grow[lane + 64 * k];
        if (USE_V) {
            float4 vvv = vrow[lane + 64 * k];
            x[4*k+0] = gg.x + vvv.x; x[4*k+1] = gg.y + vvv.y;
            x[4*k+2] = gg.z + vvv.z; x[4*k+3] = gg.w + vvv.w;
        } else {
            x[4*k+0] = gg.x; x[4*k+1] = gg.y; x[4*k+2] = gg.z; x[4*k+3] = gg.w;
        }
    }
    float m = -INFINITY;
    #pragma unroll
    for (int k = 0; k < 16; k++) m = fmaxf(m, x[k]);
    #pragma unroll
    for (int off = 32; off; off >>= 1) m = fmaxf(m, __shfl_xor(m, off));
    float s = 0.f;
    #pragma unroll
    for (int k = 0; k < 16; k++) s += __expf(x[k] - m);
    #pragma unroll
    for (int off = 32; off; off >>= 1) s += __shfl_xor(s, off);
    if (lane == 0) t[row] = -(m + __logf(s));
}

__global__ __launch_bounds__(256) void col_step(const float* __restrict__ g,
                                                const float* __restrict__ t,
                                                float* __restrict__ v) {
    const int b = blockIdx.x >> 4, tile = blockIdx.x & 15;
    const int tx = threadIdx.x & 63, ty = threadIdx.x >> 6;
    const int j = tile * 64 + tx;
    const float* gp = g + ((size_t)b << 20) + j;
    const float* tp = t + (b << 10);
    float m = -INFINITY, s = 0.f;
    for (int it = 0; it < 256; it += 8) {
        float xv[8];
        #pragma unroll
        for (int u2 = 0; u2 < 8; u2++) {
            int i = ((it + u2) << 2) + ty;
            xv[u2] = gp[(size_t)i << 10] + tp[i];
        }
        #pragma unroll
        for (int u2 = 0; u2 < 8; u2++) {
            float nm = fmaxf(m, xv[u2]);
            s = s * __expf(m - nm) + __expf(xv[u2] - nm);
            m = nm;
        }
    }
    __shared__ float sm[4][64];
    __shared__ float ss[4][64];
    sm[ty][tx] = m; ss[ty][tx] = s;
    __syncthreads();
    if (ty == 0) {
        float M = sm[0][tx], S = ss[0][tx];
        #pragma unroll
        for (int k = 1; k < 4; k++) {
            float mk = sm[k][tx], sk = ss[k][tx];
            float nm = fmaxf(M, mk);
            S = S * __expf(M - nm) + sk * __expf(mk - nm);
            M = nm;
        }
        v[(b << 10) + j] = -(M + __logf(S));
    }
}

__global__ __launch_bounds__(256) void finalize_k(const float* __restrict__ g,
                                                  const float* __restrict__ t,
                                                  const float* __restrict__ v,
                                                  float* __restrict__ out) {
    const size_t idx4 = (size_t)blockIdx.x * 256 + threadIdx.x;
    const size_t base = idx4 << 2;
    const int row = (int)(base >> 10), b = row >> 10;
    const int j = (int)(base & 1023);
    const float ti = t[row];
    float4 gg = ((const float4*)g)[idx4];
    float4 vvv = ((const float4*)(v + ((size_t)b << 10)))[j >> 2];
    float4 o;
    o.x = __expf(gg.x + ti + vvv.x);
    o.y = __expf(gg.y + ti + vvv.y);
    o.z = __expf(gg.z + ti + vvv.z);
    o.w = __expf(gg.w + ti + vvv.w);
    ((float4*)out)[idx4] = o;
}

extern "C" void kernel_launch(void* const* d_in, const int* in_sizes, int n_in,
                              void* d_out, int out_size, void* d_ws, size_t ws_size,
                              hipStream_t stream) {
    const float* g = (const float*)d_in[3];   // gumbel; inputs 0..2 dead
    float* out = (float*)d_out;
    // ws: [0,128)   barrier counters (32 x u32)
    //     [4096, 4096 + 2*32*8*1024*4) double-buffered col partials (2 MB)
    const size_t need = 4096 + 2ull * BB * 8 * NN * sizeof(float);

    if (ws_size >= need) {
        unsigned* ctr = (unsigned*)d_ws;
        float* wscol = (float*)((char*)d_ws + 4096);
        init_ctr<<<1, 64, 0, stream>>>(ctr);
        sinkhorn_persist<<<256, 1024, 0, stream>>>(g, out, wscol, ctr);
    } else {
        float* t = (float*)d_ws;
        float* v = t + BB * NN;
        row_step<false><<<8192, 256, 0, stream>>>(g, nullptr, t);
        col_step<<<512, 256, 0, stream>>>(g, t, v);
        for (int it = 1; it < 20; it++) {
            row_step<true><<<8192, 256, 0, stream>>>(g, v, t);
            col_step<<<512, 256, 0, stream>>>(g, t, v);
        }
        finalize_k<<<32768, 256, 0, stream>>>(g, t, v, out);
    }
}